// Round 7
// baseline (14328.157 us; speedup 1.0000x reference)
//
#include <hip/hip_runtime.h>
#include <math.h>

#define T_STEPS 400
#define BATCH   32
#define HID     1024
#define MROWS   (T_STEPS * BATCH)   // 12800
#define NCLS    3500
#define NG      8                    // batch groups
#define BPG     4                    // batch rows per group
#define CPG     32                   // blocks (column slices) per group
#define JS      32                   // columns per block
#define EPS     1e-6f

typedef __attribute__((ext_vector_type(8))) short short8v;   // 8 bf16 (4 VGPR)
typedef __attribute__((ext_vector_type(4))) float f32x4;

__device__ __forceinline__ unsigned short bf16_rne(float x) {
  unsigned u = __builtin_bit_cast(unsigned, x);
  unsigned r = u + 0x7FFFu + ((u >> 16) & 1u);
  return (unsigned short)(r >> 16);
}

// stage a 128x32 fp32 tile into hi/lo bf16 LDS tiles (chunk-XOR swizzled).
__device__ __forceinline__ void stage_tile(
    const float* __restrict__ src, int rowlim, int row0, int ld,
    int k0, int K, unsigned short* hi, unsigned short* lo, int tid) {
  #pragma unroll
  for (int it = 0; it < 2; ++it) {
    const int task = tid + 256 * it;          // 512 tasks: 128 rows x 4 chunks
    const int r = task >> 2, q = task & 3;
    const int gr = row0 + r;
    const bool rok = gr < rowlim;
    const float* p = src + (size_t)gr * ld + k0 + q * 8;
    float x[8];
    if (rok && (k0 + 32 <= K)) {
      float4 v0 = *(const float4*)p;
      float4 v1 = *(const float4*)(p + 4);
      x[0] = v0.x; x[1] = v0.y; x[2] = v0.z; x[3] = v0.w;
      x[4] = v1.x; x[5] = v1.y; x[6] = v1.z; x[7] = v1.w;
    } else {
      #pragma unroll
      for (int j = 0; j < 8; ++j)
        x[j] = (rok && (k0 + q * 8 + j) < K) ? p[j] : 0.f;
    }
    unsigned hp[4], lp[4];
    #pragma unroll
    for (int j = 0; j < 4; ++j) {
      unsigned short h0 = bf16_rne(x[2 * j]), h1 = bf16_rne(x[2 * j + 1]);
      float f0 = __builtin_bit_cast(float, (unsigned)h0 << 16);
      float f1 = __builtin_bit_cast(float, (unsigned)h1 << 16);
      unsigned short l0 = bf16_rne(x[2 * j] - f0), l1 = bf16_rne(x[2 * j + 1] - f1);
      hp[j] = (unsigned)h0 | ((unsigned)h1 << 16);
      lp[j] = (unsigned)l0 | ((unsigned)l1 << 16);
    }
    const int idx = (r * 4 + (q ^ (r & 3))) * 8;   // 16B-chunk swizzle
    *(uint4*)&hi[idx] = make_uint4(hp[0], hp[1], hp[2], hp[3]);
    *(uint4*)&lo[idx] = make_uint4(lp[0], lp[1], lp[2], lp[3]);
  }
}

// ---------------- MFMA GEMM: C[M][N] = A[M][K] @ W[N][K]^T + bias[N] ----------------
template <int NPASS>
__global__ __launch_bounds__(256) void gemm_mfma(
    const float* __restrict__ A, const float* __restrict__ W,
    const float* __restrict__ bias, float* __restrict__ C,
    int M, int N, int K) {
  __shared__ unsigned short Ah[128 * 32], Al[128 * 32];
  __shared__ unsigned short Bh[128 * 32], Bl[128 * 32];
  const int tid = threadIdx.x;
  const int m0 = blockIdx.y * 128, n0 = blockIdx.x * 128;
  const int w = tid >> 6, lane = tid & 63;
  const int rlow = lane & 15, ksel = lane >> 4;

  f32x4 acc[8][2];
  #pragma unroll
  for (int i = 0; i < 8; ++i) {
    acc[i][0] = (f32x4)(0.f);
    acc[i][1] = (f32x4)(0.f);
  }

  for (int k0 = 0; k0 < K; k0 += 32) {
    __syncthreads();
    stage_tile(A, M, m0, K, k0, K, Ah, Al, tid);
    stage_tile(W, N, n0, K, k0, K, Bh, Bl, tid);
    __syncthreads();

    short8v wh[2], wl[2];
    #pragma unroll
    for (int nf = 0; nf < 2; ++nf) {
      const int rn = w * 32 + nf * 16 + rlow;
      const int idx = (rn * 4 + (ksel ^ (rn & 3))) * 8;
      wh[nf] = *(const short8v*)&Bh[idx];
      if (NPASS == 3) wl[nf] = *(const short8v*)&Bl[idx];
    }
    #pragma unroll
    for (int i = 0; i < 8; ++i) {
      const int ra = i * 16 + rlow;
      const int idx = (ra * 4 + (ksel ^ (ra & 3))) * 8;
      short8v ah = *(const short8v*)&Ah[idx];
      if (NPASS == 3) {
        short8v al = *(const short8v*)&Al[idx];
        acc[i][0] = __builtin_amdgcn_mfma_f32_16x16x32_bf16(ah, wh[0], acc[i][0], 0, 0, 0);
        acc[i][0] = __builtin_amdgcn_mfma_f32_16x16x32_bf16(al, wh[0], acc[i][0], 0, 0, 0);
        acc[i][0] = __builtin_amdgcn_mfma_f32_16x16x32_bf16(ah, wl[0], acc[i][0], 0, 0, 0);
        acc[i][1] = __builtin_amdgcn_mfma_f32_16x16x32_bf16(ah, wh[1], acc[i][1], 0, 0, 0);
        acc[i][1] = __builtin_amdgcn_mfma_f32_16x16x32_bf16(al, wh[1], acc[i][1], 0, 0, 0);
        acc[i][1] = __builtin_amdgcn_mfma_f32_16x16x32_bf16(ah, wl[1], acc[i][1], 0, 0, 0);
      } else {
        acc[i][0] = __builtin_amdgcn_mfma_f32_16x16x32_bf16(ah, wh[0], acc[i][0], 0, 0, 0);
        acc[i][1] = __builtin_amdgcn_mfma_f32_16x16x32_bf16(ah, wh[1], acc[i][1], 0, 0, 0);
      }
    }
  }

  int col[2]; float bb[2]; bool cok[2];
  #pragma unroll
  for (int nf = 0; nf < 2; ++nf) {
    col[nf] = n0 + w * 32 + nf * 16 + rlow;
    cok[nf] = col[nf] < N;
    bb[nf] = cok[nf] ? bias[col[nf]] : 0.f;
  }
  #pragma unroll
  for (int i = 0; i < 8; ++i) {
    const int row = m0 + i * 16 + ksel * 4;
    #pragma unroll
    for (int nf = 0; nf < 2; ++nf) {
      if (cok[nf]) {
        float* cp = C + (size_t)row * N + col[nf];
        cp[0 * N] = acc[i][nf][0] + bb[nf];
        cp[1 * N] = acc[i][nf][1] + bb[nf];
        cp[2 * N] = acc[i][nf][2] + bb[nf];
        cp[3 * N] = acc[i][nf][3] + bb[nf];
      }
    }
  }
}

// ---------------- transpose 1024x1024: out[k][j] = in[j][k] ----------------
__global__ void transpose1024(const float* __restrict__ in, float* __restrict__ out) {
  __shared__ float tile[32][33];
  const int bx = blockIdx.x * 32, by = blockIdx.y * 32;
  const int tx = threadIdx.x, ty = threadIdx.y;  // 32 x 8
  #pragma unroll
  for (int i = 0; i < 32; i += 8)
    tile[ty + i][tx] = in[(size_t)(by + ty + i) * HID + bx + tx];
  __syncthreads();
  #pragma unroll
  for (int i = 0; i < 32; i += 8)
    out[(size_t)(bx + ty + i) * HID + by + tx] = tile[tx][ty + i];
}

// ---------------- scan: self-validating tagged publish {f32,tag} — no flags, no drains ----------------
// grid = 256 blocks x 256 thr. XCD-pinned: g = blk&7 (one XCD per group), c = blk>>3.
// publish: 64-bit relaxed agent atomics {value, tag=t+1} into parity buffer (t&1).
// consume: poll-load own 16 entries until tag matches exactly (replay-safe).
__global__ __launch_bounds__(256, 1) void scan_layer(
    const float* __restrict__ wx, const float* __restrict__ uhT,
    float* __restrict__ h_all, float* __restrict__ pre_all,
    unsigned long long* __restrict__ a_pub,   // [2][NG][BPG][HID] tagged
    const float* __restrict__ gamma, const float* __restrict__ beta,
    int skip_sub) {
  const int tid  = threadIdx.x;
  const int g    = blockIdx.x & 7;    // XCD-pinned group
  const int c    = blockIdx.x >> 3;
  const int lane = tid & 63;
  const int wv   = tid >> 6;          // wave 0..3
  const int jw   = tid & 3;
  const int ks   = tid >> 2;          // 0..63
  const int col0 = c * JS + jw * 8;

  __shared__ float h_lds[HID * BPG];      // flat [k*4+b], 16KB
  __shared__ float a_lds[BPG * HID];      // flat [b*1024+k], 16KB
  __shared__ float partial[4][BPG][JS];   // per-wave partials, 2KB
  __shared__ float stats_lds[BPG][2];
  __shared__ float g_lds[HID], be_lds[HID];

  for (int k = tid; k < HID; k += 256) { g_lds[k] = gamma[k]; be_lds[k] = beta[k]; }

  // persistent Uh slice in registers: rows ks+64i, cols col0..col0+7
  float4 u0[16], u1[16];
  #pragma unroll
  for (int i = 0; i < 16; ++i) {
    const float* p = uhT + (size_t)(ks + 64 * i) * HID + col0;
    u0[i] = *(const float4*)p;
    u1[i] = *(const float4*)(p + 4);
  }
  __syncthreads();

  for (int t = 0; t < T_STEPS; ++t) {
    const int par = t & 1;
    unsigned long long* apub_t = a_pub + ((size_t)par * NG + g) * (BPG * HID);

    // issue wx / pre loads early (independent of h)
    float at0 = 0.f, pre_old = 0.f;
    size_t gidx = 0;
    if (tid < 128) {
      const int b = tid >> 5, j = tid & 31;
      gidx = ((size_t)t * BATCH + g * BPG + b) * HID + c * JS + j;
      at0 = wx[gidx];
      pre_old = skip_sub ? 0.f : pre_all[gidx];
    }

    if (t > 0) {
      float pacc[4][8];
      #pragma unroll
      for (int b = 0; b < 4; ++b)
        #pragma unroll
        for (int q = 0; q < 8; ++q) pacc[b][q] = 0.f;
      #pragma unroll
      for (int i = 0; i < 16; ++i) {
        float4 h4 = *(const float4*)&h_lds[(ks + 64 * i) * 4];  // 2-way: free
        #pragma unroll
        for (int b = 0; b < 4; ++b) {
          float hb = ((const float*)&h4)[b];
          pacc[b][0] += hb * u0[i].x; pacc[b][1] += hb * u0[i].y;
          pacc[b][2] += hb * u0[i].z; pacc[b][3] += hb * u0[i].w;
          pacc[b][4] += hb * u1[i].x; pacc[b][5] += hb * u1[i].y;
          pacc[b][6] += hb * u1[i].z; pacc[b][7] += hb * u1[i].w;
        }
      }
      // reduce 16 k-strips within wave (lane bits 2..5)
      #pragma unroll
      for (int b = 0; b < 4; ++b)
        #pragma unroll
        for (int q = 0; q < 8; ++q) {
          float v = pacc[b][q];
          v += __shfl_xor(v, 4);
          v += __shfl_xor(v, 8);
          v += __shfl_xor(v, 16);
          v += __shfl_xor(v, 32);
          pacc[b][q] = v;
        }
      if ((lane >> 2) == 0) {   // lanes 0..3, one per jw
        #pragma unroll
        for (int b = 0; b < 4; ++b) {
          *(float4*)&partial[wv][b][jw * 8]     = *(const float4*)&pacc[b][0];
          *(float4*)&partial[wv][b][jw * 8 + 4] = *(const float4*)&pacc[b][4];
        }
      }
    }
    __syncthreads();

    // finalize a-slice; publish {value, tag} — self-validating, no drain needed
    if (tid < 128) {
      const int b = tid >> 5, j = tid & 31;
      float red = 0.f;
      if (t > 0)
        red = partial[0][b][j] + partial[1][b][j] + partial[2][b][j] + partial[3][b][j];
      float at = at0 + red;
      pre_all[gidx] = at;
      float av = at - pre_old;
      unsigned long long pk =
          ((unsigned long long)(unsigned)(t + 1) << 32) |
          (unsigned long long)__builtin_bit_cast(unsigned, av);
      __hip_atomic_store(&apub_t[(size_t)b * HID + c * JS + j], pk,
                         __ATOMIC_RELAXED, __HIP_MEMORY_SCOPE_AGENT);
    }

    // poll-read the 16 tagged entries this thread stages into a_lds
    {
      const unsigned wanted = (unsigned)(t + 1);
      unsigned pend = 0xFFFFu;
      float vals[16];
      while (pend) {
        #pragma unroll
        for (int s = 0; s < 16; ++s) {
          if (pend & (1u << s)) {
            const int b = s >> 2, j = s & 3;
            unsigned long long pk = __hip_atomic_load(
                &apub_t[(size_t)b * HID + tid + 256 * j],
                __ATOMIC_RELAXED, __HIP_MEMORY_SCOPE_AGENT);
            if ((unsigned)(pk >> 32) == wanted) {
              vals[s] = __builtin_bit_cast(float, (unsigned)pk);
              pend &= ~(1u << s);
            }
          }
        }
        if (pend) __builtin_amdgcn_s_sleep(1);
      }
      #pragma unroll
      for (int s = 0; s < 16; ++s) {
        const int b = s >> 2, j = s & 3;
        a_lds[b * HID + tid + 256 * j] = vals[s];
      }
    }
    __syncthreads();

    // stats per batch row (wave wv <-> row b=wv), ddof=1, eps on std
    {
      float s1 = 0.f, s2 = 0.f;
      #pragma unroll
      for (int i = 0; i < 16; ++i) {
        float v = a_lds[wv * HID + i * 64 + lane];
        s1 += v; s2 += v * v;
      }
      #pragma unroll
      for (int m = 1; m <= 32; m <<= 1) { s1 += __shfl_xor(s1, m); s2 += __shfl_xor(s2, m); }
      if (lane == 0) {
        float mean = s1 * (1.f / HID);
        float var = (s2 - (float)HID * mean * mean) * (1.f / (float)(HID - 1));
        stats_lds[wv][0] = mean;
        stats_lds[wv][1] = sqrtf(fmaxf(var, 0.f)) + EPS;
      }
    }
    __syncthreads();

    // h = relu(LN(a)) for rows k = tid + 256*j; write h_lds[k*4+b] (2-way: free)
    {
      float mean0 = stats_lds[0][0], rd0 = 1.f / stats_lds[0][1];
      float mean1 = stats_lds[1][0], rd1 = 1.f / stats_lds[1][1];
      float mean2 = stats_lds[2][0], rd2 = 1.f / stats_lds[2][1];
      float mean3 = stats_lds[3][0], rd3 = 1.f / stats_lds[3][1];
      #pragma unroll
      for (int j = 0; j < 4; ++j) {
        const int k = tid + 256 * j;
        float gk = g_lds[k], bk = be_lds[k];
        float h0 = fmaxf(gk * (a_lds[0 * HID + k] - mean0) * rd0 + bk, 0.f);
        float h1 = fmaxf(gk * (a_lds[1 * HID + k] - mean1) * rd1 + bk, 0.f);
        float h2 = fmaxf(gk * (a_lds[2 * HID + k] - mean2) * rd2 + bk, 0.f);
        float h3 = fmaxf(gk * (a_lds[3 * HID + k] - mean3) * rd3 + bk, 0.f);
        *(float4*)&h_lds[k * 4] = make_float4(h0, h1, h2, h3);
        if (c == 0) {
          h_all[((size_t)t * BATCH + g * BPG + 0) * HID + k] = h0;
          h_all[((size_t)t * BATCH + g * BPG + 1) * HID + k] = h1;
          h_all[((size_t)t * BATCH + g * BPG + 2) * HID + k] = h2;
          h_all[((size_t)t * BATCH + g * BPG + 3) * HID + k] = h3;
        }
      }
    }
    __syncthreads();
  }
}

// ---------------- softmax + loss/err per row ----------------
__global__ __launch_bounds__(256) void softmax_loss(
    float* __restrict__ out, const int* __restrict__ lab, float* __restrict__ acc) {
  __shared__ float rowbuf[NCLS];
  __shared__ float rv[4]; __shared__ int ri[4]; __shared__ float rs[4];
  __shared__ float shv[2];
  __shared__ int shidx;
  const int m = blockIdx.x;
  float* row = out + (size_t)m * NCLS;
  const int tid = threadIdx.x;
  const int lane = tid & 63, wid = tid >> 6;

  float vmax = -1e30f; int vidx = 0x7fffffff;
  for (int c = tid; c < NCLS; c += 256) {
    float v = row[c];
    rowbuf[c] = v;
    if (v > vmax) { vmax = v; vidx = c; }
  }
  #pragma unroll
  for (int off = 32; off; off >>= 1) {
    float ov = __shfl_down(vmax, off);
    int oi = __shfl_down(vidx, off);
    if (ov > vmax || (ov == vmax && oi < vidx)) { vmax = ov; vidx = oi; }
  }
  if (lane == 0) { rv[wid] = vmax; ri[wid] = vidx; }
  __syncthreads();
  if (tid == 0) {
    float bm = rv[0]; int bi = ri[0];
    for (int w = 1; w < 4; ++w)
      if (rv[w] > bm || (rv[w] == bm && ri[w] < bi)) { bm = rv[w]; bi = ri[w]; }
    shv[0] = bm; shidx = bi;
  }
  __syncthreads();
  float gmax = shv[0];
  float s = 0.f;
  for (int c = tid; c < NCLS; c += 256) s += expf(rowbuf[c] - gmax);
  #pragma unroll
  for (int off = 32; off; off >>= 1) s += __shfl_down(s, off);
  if (lane == 0) rs[wid] = s;
  __syncthreads();
  if (tid == 0) shv[1] = rs[0] + rs[1] + rs[2] + rs[3];
  __syncthreads();
  float lse = logf(shv[1]);
  for (int c = tid; c < NCLS; c += 256) row[c] = rowbuf[c] - gmax - lse;
  if (tid == 0) {
    int lb = lab[m];
    float nll = -(rowbuf[lb] - gmax - lse);
    atomicAdd(acc + 0, nll);
    atomicAdd(acc + 1, (shidx != lb) ? 1.f : 0.f);
  }
}

__global__ void init_acc(float* acc) { acc[threadIdx.x] = 0.f; }

__global__ void finalize_out(const float* __restrict__ acc, float* __restrict__ out) {
  out[0] = acc[0] * (1.f / (float)MROWS);
  out[1] = acc[1] * (1.f / (float)MROWS);
}

extern "C" void kernel_launch(void* const* d_in, const int* in_sizes, int n_in,
                              void* d_out, int out_size, void* d_ws, size_t ws_size,
                              hipStream_t stream) {
  const float* x     = (const float*)d_in[0];
  const int*   lab   = (const int*)d_in[1];
  const float* wx0_w = (const float*)d_in[3];
  const float* wx0_b = (const float*)d_in[4];
  const float* wx_w  = (const float*)d_in[5];
  const float* wx_b  = (const float*)d_in[6];
  const float* uh_w  = (const float*)d_in[7];
  const float* ln_g  = (const float*)d_in[8];
  const float* ln_b  = (const float*)d_in[9];
  const float* fco_w = (const float*)d_in[10];
  const float* fco_b = (const float*)d_in[11];
  float* out = (float*)d_out;

  float* wsf = (float*)d_ws;
  size_t off = 0;
  auto carve = [&](size_t n) { float* p = wsf + off; off += (n + 63) & ~(size_t)63; return p; };
  float* uhT   = carve((size_t)HID * HID);                     //  4 MB
  float* wxbuf = carve((size_t)MROWS * HID);                   // 50 MB
  float* h_all = carve((size_t)MROWS * HID);                   // 50 MB
  float* pre   = carve((size_t)MROWS * HID);                   // 50 MB
  unsigned long long* a_pub =
      (unsigned long long*)carve((size_t)2 * 2 * NG * BPG * HID);  // 512 KB tagged
  float* acc   = carve(64);

  init_acc<<<1, 2, 0, stream>>>(acc);

  for (int layer = 0; layer < 4; ++layer) {
    if (layer == 0) {
      gemm_mfma<3><<<dim3(HID / 128, MROWS / 128), 256, 0, stream>>>(
          x, wx0_w, wx0_b, wxbuf, MROWS, HID, 440);
    } else {
      gemm_mfma<3><<<dim3(HID / 128, MROWS / 128), 256, 0, stream>>>(
          h_all, wx_w + (size_t)(layer - 1) * HID * HID,
          wx_b + (size_t)(layer - 1) * HID, wxbuf, MROWS, HID, HID);
    }
    transpose1024<<<dim3(32, 32), dim3(32, 8), 0, stream>>>(
        uh_w + (size_t)layer * HID * HID, uhT);

    scan_layer<<<dim3(NG * CPG), 256, 0, stream>>>(
        wxbuf, uhT, h_all, pre, a_pub,
        ln_g + (size_t)layer * HID, ln_b + (size_t)layer * HID,
        (layer == 0) ? 1 : 0);
  }

  gemm_mfma<1><<<dim3((NCLS + 127) / 128, MROWS / 128), 256, 0, stream>>>(
      h_all, fco_w, fco_b, out + 2, MROWS, NCLS, HID);
  softmax_loss<<<MROWS, 256, 0, stream>>>(out + 2, lab, acc);
  finalize_out<<<1, 1, 0, stream>>>(acc, out);
}

// Round 8
// 10319.779 us; speedup vs baseline: 1.3884x; 1.3884x over previous
//
#include <hip/hip_runtime.h>
#include <math.h>

#define T_STEPS 400
#define BATCH   32
#define HID     1024
#define MROWS   (T_STEPS * BATCH)   // 12800
#define NCLS    3500
#define NG      8                    // batch groups
#define BPG     4                    // batch rows per group
#define CPG     32                   // blocks (column slices) per group
#define JS      32                   // columns per block
#define EPS     1e-6f
#define SLOTP   8                    // ints per progress slot (32B padding)

typedef __attribute__((ext_vector_type(8))) short short8v;   // 8 bf16 (4 VGPR)
typedef __attribute__((ext_vector_type(4))) float f32x4;

__device__ __forceinline__ unsigned short bf16_rne(float x) {
  unsigned u = __builtin_bit_cast(unsigned, x);
  unsigned r = u + 0x7FFFu + ((u >> 16) & 1u);
  return (unsigned short)(r >> 16);
}

// stage a 128x32 fp32 tile into hi/lo bf16 LDS tiles (chunk-XOR swizzled).
__device__ __forceinline__ void stage_tile(
    const float* __restrict__ src, int rowlim, int row0, int ld,
    int k0, int K, unsigned short* hi, unsigned short* lo, int tid) {
  #pragma unroll
  for (int it = 0; it < 2; ++it) {
    const int task = tid + 256 * it;          // 512 tasks: 128 rows x 4 chunks
    const int r = task >> 2, q = task & 3;
    const int gr = row0 + r;
    const bool rok = gr < rowlim;
    const float* p = src + (size_t)gr * ld + k0 + q * 8;
    float x[8];
    if (rok && (k0 + 32 <= K)) {
      float4 v0 = *(const float4*)p;
      float4 v1 = *(const float4*)(p + 4);
      x[0] = v0.x; x[1] = v0.y; x[2] = v0.z; x[3] = v0.w;
      x[4] = v1.x; x[5] = v1.y; x[6] = v1.z; x[7] = v1.w;
    } else {
      #pragma unroll
      for (int j = 0; j < 8; ++j)
        x[j] = (rok && (k0 + q * 8 + j) < K) ? p[j] : 0.f;
    }
    unsigned hp[4], lp[4];
    #pragma unroll
    for (int j = 0; j < 4; ++j) {
      unsigned short h0 = bf16_rne(x[2 * j]), h1 = bf16_rne(x[2 * j + 1]);
      float f0 = __builtin_bit_cast(float, (unsigned)h0 << 16);
      float f1 = __builtin_bit_cast(float, (unsigned)h1 << 16);
      unsigned short l0 = bf16_rne(x[2 * j] - f0), l1 = bf16_rne(x[2 * j + 1] - f1);
      hp[j] = (unsigned)h0 | ((unsigned)h1 << 16);
      lp[j] = (unsigned)l0 | ((unsigned)l1 << 16);
    }
    const int idx = (r * 4 + (q ^ (r & 3))) * 8;   // 16B-chunk swizzle
    *(uint4*)&hi[idx] = make_uint4(hp[0], hp[1], hp[2], hp[3]);
    *(uint4*)&lo[idx] = make_uint4(lp[0], lp[1], lp[2], lp[3]);
  }
}

// ---------------- MFMA GEMM: C[M][N] = A[M][K] @ W[N][K]^T + bias[N] ----------------
template <int NPASS>
__global__ __launch_bounds__(256) void gemm_mfma(
    const float* __restrict__ A, const float* __restrict__ W,
    const float* __restrict__ bias, float* __restrict__ C,
    int M, int N, int K) {
  __shared__ unsigned short Ah[128 * 32], Al[128 * 32];
  __shared__ unsigned short Bh[128 * 32], Bl[128 * 32];
  const int tid = threadIdx.x;
  const int m0 = blockIdx.y * 128, n0 = blockIdx.x * 128;
  const int w = tid >> 6, lane = tid & 63;
  const int rlow = lane & 15, ksel = lane >> 4;

  f32x4 acc[8][2];
  #pragma unroll
  for (int i = 0; i < 8; ++i) {
    acc[i][0] = (f32x4)(0.f);
    acc[i][1] = (f32x4)(0.f);
  }

  for (int k0 = 0; k0 < K; k0 += 32) {
    __syncthreads();
    stage_tile(A, M, m0, K, k0, K, Ah, Al, tid);
    stage_tile(W, N, n0, K, k0, K, Bh, Bl, tid);
    __syncthreads();

    short8v wh[2], wl[2];
    #pragma unroll
    for (int nf = 0; nf < 2; ++nf) {
      const int rn = w * 32 + nf * 16 + rlow;
      const int idx = (rn * 4 + (ksel ^ (rn & 3))) * 8;
      wh[nf] = *(const short8v*)&Bh[idx];
      if (NPASS == 3) wl[nf] = *(const short8v*)&Bl[idx];
    }
    #pragma unroll
    for (int i = 0; i < 8; ++i) {
      const int ra = i * 16 + rlow;
      const int idx = (ra * 4 + (ksel ^ (ra & 3))) * 8;
      short8v ah = *(const short8v*)&Ah[idx];
      if (NPASS == 3) {
        short8v al = *(const short8v*)&Al[idx];
        acc[i][0] = __builtin_amdgcn_mfma_f32_16x16x32_bf16(ah, wh[0], acc[i][0], 0, 0, 0);
        acc[i][0] = __builtin_amdgcn_mfma_f32_16x16x32_bf16(al, wh[0], acc[i][0], 0, 0, 0);
        acc[i][0] = __builtin_amdgcn_mfma_f32_16x16x32_bf16(ah, wl[0], acc[i][0], 0, 0, 0);
        acc[i][1] = __builtin_amdgcn_mfma_f32_16x16x32_bf16(ah, wh[1], acc[i][1], 0, 0, 0);
        acc[i][1] = __builtin_amdgcn_mfma_f32_16x16x32_bf16(al, wh[1], acc[i][1], 0, 0, 0);
        acc[i][1] = __builtin_amdgcn_mfma_f32_16x16x32_bf16(ah, wl[1], acc[i][1], 0, 0, 0);
      } else {
        acc[i][0] = __builtin_amdgcn_mfma_f32_16x16x32_bf16(ah, wh[0], acc[i][0], 0, 0, 0);
        acc[i][1] = __builtin_amdgcn_mfma_f32_16x16x32_bf16(ah, wh[1], acc[i][1], 0, 0, 0);
      }
    }
  }

  int col[2]; float bb[2]; bool cok[2];
  #pragma unroll
  for (int nf = 0; nf < 2; ++nf) {
    col[nf] = n0 + w * 32 + nf * 16 + rlow;
    cok[nf] = col[nf] < N;
    bb[nf] = cok[nf] ? bias[col[nf]] : 0.f;
  }
  #pragma unroll
  for (int i = 0; i < 8; ++i) {
    const int row = m0 + i * 16 + ksel * 4;
    #pragma unroll
    for (int nf = 0; nf < 2; ++nf) {
      if (cok[nf]) {
        float* cp = C + (size_t)row * N + col[nf];
        cp[0 * N] = acc[i][nf][0] + bb[nf];
        cp[1 * N] = acc[i][nf][1] + bb[nf];
        cp[2 * N] = acc[i][nf][2] + bb[nf];
        cp[3 * N] = acc[i][nf][3] + bb[nf];
      }
    }
  }
}

// ---------------- transpose 1024x1024: out[k][j] = in[j][k] ----------------
__global__ void transpose1024(const float* __restrict__ in, float* __restrict__ out) {
  __shared__ float tile[32][33];
  const int bx = blockIdx.x * 32, by = blockIdx.y * 32;
  const int tx = threadIdx.x, ty = threadIdx.y;  // 32 x 8
  #pragma unroll
  for (int i = 0; i < 32; i += 8)
    tile[ty + i][tx] = in[(size_t)(by + ty + i) * HID + bx + tx];
  __syncthreads();
  #pragma unroll
  for (int i = 0; i < 32; i += 8)
    out[(size_t)(bx + ty + i) * HID + by + tx] = tile[tx][ty + i];
}

// ---------------- scan: per-block progress slots (no RMW), IF-coherent atomics ----------------
// Round-6 proven structure + all-wave slot poll (one less barrier) + t+1 wx/pre prefetch.
__global__ __launch_bounds__(256, 1) void scan_layer(
    const float* __restrict__ wx, const float* __restrict__ uhT,
    float* __restrict__ h_all, float* __restrict__ pre_all,
    float* __restrict__ a_pub,        // [2][NG][BPG][HID]
    int* __restrict__ prog,           // [NG][CPG][SLOTP]
    const float* __restrict__ gamma, const float* __restrict__ beta,
    int skip_sub) {
  const int tid  = threadIdx.x;
  const int g    = blockIdx.x >> 5;
  const int c    = blockIdx.x & 31;
  const int lane = tid & 63;
  const int wv   = tid >> 6;          // wave 0..3
  const int jw   = tid & 3;
  const int ks   = tid >> 2;          // 0..63
  const int col0 = c * JS + jw * 8;

  int* prog_g = prog + (size_t)g * CPG * SLOTP;

  __shared__ float h_lds[HID * BPG];      // flat [k*4+b], 16KB
  __shared__ float a_lds[BPG * HID];      // flat [b*1024+k], 16KB
  __shared__ float partial[4][BPG][JS];   // per-wave partials, 2KB
  __shared__ float stats_lds[BPG][2];
  __shared__ float g_lds[HID], be_lds[HID];

  for (int k = tid; k < HID; k += 256) { g_lds[k] = gamma[k]; be_lds[k] = beta[k]; }

  // persistent Uh slice in registers: rows ks+64i, cols col0..col0+7
  float4 u0[16], u1[16];
  #pragma unroll
  for (int i = 0; i < 16; ++i) {
    const float* p = uhT + (size_t)(ks + 64 * i) * HID + col0;
    u0[i] = *(const float4*)p;
    u1[i] = *(const float4*)(p + 4);
  }
  __syncthreads();

  // prefetch wx/pre for t=0
  float at0 = 0.f, pre_old = 0.f;
  size_t gidx = 0;
  if (tid < 128) {
    const int b = tid >> 5, j = tid & 31;
    gidx = ((size_t)0 * BATCH + g * BPG + b) * HID + c * JS + j;
    at0 = wx[gidx];
    pre_old = skip_sub ? 0.f : pre_all[gidx];
  }

  for (int t = 0; t < T_STEPS; ++t) {
    const int par = t & 1;
    float* apub_t = a_pub + ((size_t)par * NG + g) * (BPG * HID);

    if (t > 0) {
      float pacc[4][8];
      #pragma unroll
      for (int b = 0; b < 4; ++b)
        #pragma unroll
        for (int q = 0; q < 8; ++q) pacc[b][q] = 0.f;
      #pragma unroll
      for (int i = 0; i < 16; ++i) {
        float4 h4 = *(const float4*)&h_lds[(ks + 64 * i) * 4];  // 2-way: free
        #pragma unroll
        for (int b = 0; b < 4; ++b) {
          float hb = ((const float*)&h4)[b];
          pacc[b][0] += hb * u0[i].x; pacc[b][1] += hb * u0[i].y;
          pacc[b][2] += hb * u0[i].z; pacc[b][3] += hb * u0[i].w;
          pacc[b][4] += hb * u1[i].x; pacc[b][5] += hb * u1[i].y;
          pacc[b][6] += hb * u1[i].z; pacc[b][7] += hb * u1[i].w;
        }
      }
      // reduce 16 k-strips within wave (lane bits 2..5)
      #pragma unroll
      for (int b = 0; b < 4; ++b)
        #pragma unroll
        for (int q = 0; q < 8; ++q) {
          float v = pacc[b][q];
          v += __shfl_xor(v, 4);
          v += __shfl_xor(v, 8);
          v += __shfl_xor(v, 16);
          v += __shfl_xor(v, 32);
          pacc[b][q] = v;
        }
      if ((lane >> 2) == 0) {   // lanes 0..3, one per jw
        #pragma unroll
        for (int b = 0; b < 4; ++b) {
          *(float4*)&partial[wv][b][jw * 8]     = *(const float4*)&pacc[b][0];
          *(float4*)&partial[wv][b][jw * 8 + 4] = *(const float4*)&pacc[b][4];
        }
      }
    }
    __syncthreads();

    // finalize a-slice; publish via IF-coherent relaxed atomic stores (no fence)
    if (tid < 128) {
      const int b = tid >> 5, j = tid & 31;
      float red = 0.f;
      if (t > 0)
        red = partial[0][b][j] + partial[1][b][j] + partial[2][b][j] + partial[3][b][j];
      float at = at0 + red;
      pre_all[gidx] = at;
      __hip_atomic_store(&apub_t[(size_t)b * HID + c * JS + j], at - pre_old,
                         __ATOMIC_RELAXED, __HIP_MEMORY_SCOPE_AGENT);
    }
    // each thread drains its own outstanding stores before the barrier
    asm volatile("s_waitcnt vmcnt(0)" ::: "memory");
    __syncthreads();

    // announce: tid0 stores step number to own slot (all publishers drained above)
    if (tid == 0)
      __hip_atomic_store(&prog_g[c * SLOTP], t + 1,
                         __ATOMIC_RELAXED, __HIP_MEMORY_SCOPE_AGENT);

    // prefetch wx/pre for t+1 — completes under the poll window
    float at0_n = 0.f, pre_n = 0.f;
    size_t gidx_n = gidx;
    if (t + 1 < T_STEPS && tid < 128) {
      const int b = tid >> 5, j = tid & 31;
      gidx_n = ((size_t)(t + 1) * BATCH + g * BPG + b) * HID + c * JS + j;
      at0_n = wx[gidx_n];
      pre_n = skip_sub ? 0.f : pre_all[gidx_n];
    }

    // ALL waves poll the 32 slots (read-only; no barrier needed before staging)
    {
      const int* p = &prog_g[(lane & 31) * SLOTP];
      while (true) {
        int v = __hip_atomic_load(p, __ATOMIC_RELAXED, __HIP_MEMORY_SCOPE_AGENT);
        if (__all(v >= t + 1)) break;
        __builtin_amdgcn_s_sleep(1);
      }
    }

    // stage full a[4][1024] into LDS via coherent atomic loads (lane-linear)
    {
      float tmp[16];
      #pragma unroll
      for (int j = 0; j < 16; ++j)
        tmp[j] = __hip_atomic_load(&apub_t[tid + 256 * j],
                                   __ATOMIC_RELAXED, __HIP_MEMORY_SCOPE_AGENT);
      #pragma unroll
      for (int j = 0; j < 16; ++j)
        a_lds[tid + 256 * j] = tmp[j];
    }
    __syncthreads();

    // stats per batch row (wave wv <-> row b=wv), ddof=1, eps on std
    {
      float s1 = 0.f, s2 = 0.f;
      #pragma unroll
      for (int i = 0; i < 16; ++i) {
        float v = a_lds[wv * HID + i * 64 + lane];
        s1 += v; s2 += v * v;
      }
      #pragma unroll
      for (int m = 1; m <= 32; m <<= 1) { s1 += __shfl_xor(s1, m); s2 += __shfl_xor(s2, m); }
      if (lane == 0) {
        float mean = s1 * (1.f / HID);
        float var = (s2 - (float)HID * mean * mean) * (1.f / (float)(HID - 1));
        stats_lds[wv][0] = mean;
        stats_lds[wv][1] = sqrtf(fmaxf(var, 0.f)) + EPS;
      }
    }
    __syncthreads();

    // h = relu(LN(a)) for rows k = tid + 256*j; write h_lds[k*4+b] (2-way: free)
    {
      float mean0 = stats_lds[0][0], rd0 = 1.f / stats_lds[0][1];
      float mean1 = stats_lds[1][0], rd1 = 1.f / stats_lds[1][1];
      float mean2 = stats_lds[2][0], rd2 = 1.f / stats_lds[2][1];
      float mean3 = stats_lds[3][0], rd3 = 1.f / stats_lds[3][1];
      #pragma unroll
      for (int j = 0; j < 4; ++j) {
        const int k = tid + 256 * j;
        float gk = g_lds[k], bk = be_lds[k];
        float h0 = fmaxf(gk * (a_lds[0 * HID + k] - mean0) * rd0 + bk, 0.f);
        float h1 = fmaxf(gk * (a_lds[1 * HID + k] - mean1) * rd1 + bk, 0.f);
        float h2 = fmaxf(gk * (a_lds[2 * HID + k] - mean2) * rd2 + bk, 0.f);
        float h3 = fmaxf(gk * (a_lds[3 * HID + k] - mean3) * rd3 + bk, 0.f);
        *(float4*)&h_lds[k * 4] = make_float4(h0, h1, h2, h3);
        if (c == 0) {
          h_all[((size_t)t * BATCH + g * BPG + 0) * HID + k] = h0;
          h_all[((size_t)t * BATCH + g * BPG + 1) * HID + k] = h1;
          h_all[((size_t)t * BATCH + g * BPG + 2) * HID + k] = h2;
          h_all[((size_t)t * BATCH + g * BPG + 3) * HID + k] = h3;
        }
      }
    }
    __syncthreads();

    at0 = at0_n; pre_old = pre_n; gidx = gidx_n;
  }
}

// ---------------- softmax + loss/err per row (float2 loads, 8B-aligned safe) ----------------
__global__ __launch_bounds__(256) void softmax_loss(
    float* __restrict__ out, const int* __restrict__ lab, float* __restrict__ acc) {
  __shared__ float rowbuf[NCLS];
  __shared__ float rv[4]; __shared__ int ri[4]; __shared__ float rs[4];
  __shared__ float shv[2];
  __shared__ int shidx;
  const int m = blockIdx.x;
  float* row = out + (size_t)m * NCLS;
  const int tid = threadIdx.x;
  const int lane = tid & 63, wid = tid >> 6;

  float vmax = -1e30f; int vidx = 0x7fffffff;
  for (int c2 = tid; c2 < NCLS / 2; c2 += 256) {   // 1750 float2
    float2 v = *(const float2*)(row + 2 * c2);
    rowbuf[2 * c2] = v.x; rowbuf[2 * c2 + 1] = v.y;
    if (v.x > vmax) { vmax = v.x; vidx = 2 * c2; }
    if (v.y > vmax) { vmax = v.y; vidx = (v.x > v.y) ? vidx : 2 * c2 + 1; }
  }
  // NCLS even (3500): no tail
  #pragma unroll
  for (int off = 32; off; off >>= 1) {
    float ov = __shfl_down(vmax, off);
    int oi = __shfl_down(vidx, off);
    if (ov > vmax || (ov == vmax && oi < vidx)) { vmax = ov; vidx = oi; }
  }
  if (lane == 0) { rv[wid] = vmax; ri[wid] = vidx; }
  __syncthreads();
  if (tid == 0) {
    float bm = rv[0]; int bi = ri[0];
    for (int w = 1; w < 4; ++w)
      if (rv[w] > bm || (rv[w] == bm && ri[w] < bi)) { bm = rv[w]; bi = ri[w]; }
    shv[0] = bm; shidx = bi;
  }
  __syncthreads();
  float gmax = shv[0];
  float s = 0.f;
  for (int c = tid; c < NCLS; c += 256) s += expf(rowbuf[c] - gmax);
  #pragma unroll
  for (int off = 32; off; off >>= 1) s += __shfl_down(s, off);
  if (lane == 0) rs[wid] = s;
  __syncthreads();
  if (tid == 0) shv[1] = rs[0] + rs[1] + rs[2] + rs[3];
  __syncthreads();
  float lse = logf(shv[1]);
  for (int c2 = tid; c2 < NCLS / 2; c2 += 256) {
    float2 v;
    v.x = rowbuf[2 * c2] - gmax - lse;
    v.y = rowbuf[2 * c2 + 1] - gmax - lse;
    *(float2*)(row + 2 * c2) = v;
  }
  if (tid == 0) {
    int lb = lab[m];
    float nll = -(rowbuf[lb] - gmax - lse);
    atomicAdd(acc + 0, nll);
    atomicAdd(acc + 1, (shidx != lb) ? 1.f : 0.f);
  }
}

__global__ void init_acc(float* acc) { acc[threadIdx.x] = 0.f; }

__global__ void finalize_out(const float* __restrict__ acc, float* __restrict__ out) {
  out[0] = acc[0] * (1.f / (float)MROWS);
  out[1] = acc[1] * (1.f / (float)MROWS);
}

extern "C" void kernel_launch(void* const* d_in, const int* in_sizes, int n_in,
                              void* d_out, int out_size, void* d_ws, size_t ws_size,
                              hipStream_t stream) {
  const float* x     = (const float*)d_in[0];
  const int*   lab   = (const int*)d_in[1];
  const float* wx0_w = (const float*)d_in[3];
  const float* wx0_b = (const float*)d_in[4];
  const float* wx_w  = (const float*)d_in[5];
  const float* wx_b  = (const float*)d_in[6];
  const float* uh_w  = (const float*)d_in[7];
  const float* ln_g  = (const float*)d_in[8];
  const float* ln_b  = (const float*)d_in[9];
  const float* fco_w = (const float*)d_in[10];
  const float* fco_b = (const float*)d_in[11];
  float* out = (float*)d_out;

  float* wsf = (float*)d_ws;
  size_t off = 0;
  auto carve = [&](size_t n) { float* p = wsf + off; off += (n + 63) & ~(size_t)63; return p; };
  float* uhT   = carve((size_t)HID * HID);                 //  4 MB
  float* wxbuf = carve((size_t)MROWS * HID);               // 50 MB
  float* h_all = carve((size_t)MROWS * HID);               // 50 MB
  float* pre   = carve((size_t)MROWS * HID);               // 50 MB
  float* a_pub = carve((size_t)2 * NG * BPG * HID);        // 256 KB
  int*   prog  = (int*)carve((size_t)4 * NG * CPG * SLOTP); // 32 KB (4 layers)
  float* acc   = carve(64);

  (void)hipMemsetAsync(prog, 0, (size_t)4 * NG * CPG * SLOTP * sizeof(int), stream);
  init_acc<<<1, 2, 0, stream>>>(acc);

  for (int layer = 0; layer < 4; ++layer) {
    if (layer == 0) {
      gemm_mfma<3><<<dim3(HID / 128, MROWS / 128), 256, 0, stream>>>(
          x, wx0_w, wx0_b, wxbuf, MROWS, HID, 440);
    } else {
      gemm_mfma<3><<<dim3(HID / 128, MROWS / 128), 256, 0, stream>>>(
          h_all, wx_w + (size_t)(layer - 1) * HID * HID,
          wx_b + (size_t)(layer - 1) * HID, wxbuf, MROWS, HID, HID);
    }
    transpose1024<<<dim3(32, 32), dim3(32, 8), 0, stream>>>(
        uh_w + (size_t)layer * HID * HID, uhT);

    scan_layer<<<dim3(NG * CPG), 256, 0, stream>>>(
        wxbuf, uhT, h_all, pre, a_pub, prog + (size_t)layer * NG * CPG * SLOTP,
        ln_g + (size_t)layer * HID, ln_b + (size_t)layer * HID,
        (layer == 0) ? 1 : 0);
  }

  gemm_mfma<1><<<dim3((NCLS + 127) / 128, MROWS / 128), 256, 0, stream>>>(
      h_all, fco_w, fco_b, out + 2, MROWS, NCLS, HID);
  softmax_loss<<<MROWS, 256, 0, stream>>>(out + 2, lab, acc);
  finalize_out<<<1, 1, 0, stream>>>(acc, out);
}